// Round 1
// baseline (367.725 us; speedup 1.0000x reference)
//
#include <hip/hip_runtime.h>
#include <hip/hip_bf16.h>

// GCN 2-layer forward, fp32 I/O. dinv folded into stored rows:
//   h1' = dinv * (x @ W1),  agg1 = dinv * (h1'[i] + sum_nbr h1'[s])
//   h2' = dinv * (relu(agg1+b1) @ W2),  out = dinv * (h2'[i] + sum h2'[s]) + b2
// so pull kernels are pure gather+add (no per-edge norm, no dinv reads).
// Packed 4B edge records; fixed-capacity bucketed CSR build with all
// per-node atomics in LDS; bf16 h/agg storage; MFMA bf16 GEMMs.
//
// NEW this round: layer-1 gather (k_pull128) is XCD-feature-chunked.
// h1' and aggb are stored chunk-major [8][N][16 feats]; chunk = blockIdx&7
// pins each 16-feat slab (3.2 MB) to one XCD's 4 MB L2, so the random
// gather becomes an L2 hit (~17x reuse) instead of an 8x-duplicated
// compulsory miss per XCD. Waves serve 8 nodes via 8-lane groups (32 B
// granules); csr indices fetched as one 32 B vector load per group and
// broadcast with __shfl. Streaming traffic (csr4/row_ptr/deg/dinv/agg
// store) uses non-temporal hints to keep the chunk table L2-resident.
// Pipeline:
//  1) k_prep: W1,W2 -> bf16 transposed; bcur[b] = b*CAP
//  2) k_bucket: partition packed {src,dloc} by dst>>9 into ebuf
//  3) k_bcsr:  per-bucket LDS stage -> hist -> scan -> deg/dinv/row_ptr
//              -> LDS-cursor scatter -> csr4 = src
//  4) h1' = dinv*(x @ W1) -> bf16 chunk-major     (k_gemm1, MFMA)
//  5) aggb = dinv*(self+gather-sum of h1') -> bf16 chunk-major (k_pull128)
//  6) h2' = dinv*(relu(aggb+b1) @ W2) -> bf16 row-major (k_gemm2, MFMA)
//  7) out = dinv*(self+gather-sum of h2') + b2    (k_pull64)

typedef short short8v __attribute__((ext_vector_type(8)));   // 8 bf16 (4 VGPRs)
typedef float f32x4   __attribute__((ext_vector_type(4)));   // MFMA acc

#define BSHIFT 9           // bucket = dst >> 9 (span 512 nodes)
#define BSIZE  512
#define CAPSH  14          // per-bucket capacity 16384 (mean 8163, >40 sigma)
#define CAP    (1 << CAPSH)

// RNE fp32 -> bf16 (finite inputs)
__device__ __forceinline__ short f2bf(float f) {
    unsigned u = __float_as_uint(f);
    return (short)((u + 0x7fffu + ((u >> 16) & 1u)) >> 16);
}
__device__ __forceinline__ unsigned pack2bf(float a, float b) {
    return (unsigned)(unsigned short)f2bf(a) | ((unsigned)(unsigned short)f2bf(b) << 16);
}
__device__ __forceinline__ float bflo(unsigned u) { return __uint_as_float(u << 16); }
__device__ __forceinline__ float bfhi(unsigned u) { return __uint_as_float(u & 0xffff0000u); }

// ---- W prep + bucket-cursor init (one launch) ----
__global__ void k_prep(const float* __restrict__ W1, const float* __restrict__ W2,
                       short* __restrict__ w1t, short* __restrict__ w2t,
                       int* __restrict__ bcur, int nbuck) {
    int b = blockIdx.x;
    int t = threadIdx.x;
    if (b == gridDim.x - 1) {                 // last block: init bucket cursors
        if (t < nbuck) bcur[t] = t << CAPSH;
        return;
    }
    int i = b * 256 + t;                      // 96 blocks cover 24576 elems
    if (i < 128 * 128) {
        int n = i >> 7, k = i & 127;
        w1t[i] = f2bf(W1[k * 128 + n]);
    } else {
        int j = i - 128 * 128;
        int n = j >> 7, k = j & 127;
        w2t[j] = f2bf(W2[k * 64 + n]);
    }
}

// ---- partition edges into packed ebuf: entry = (src<<9) | (dst&511) ----
__global__ __launch_bounds__(256) void k_bucket(const int* __restrict__ src,
                                                const int* __restrict__ dst,
                                                int* __restrict__ bcur,
                                                unsigned* __restrict__ ebuf,
                                                int E, int nbuck) {
    __shared__ int sdst[4096];
    __shared__ int ssrc[4096];
    __shared__ int hist[256];
    __shared__ int base[256];
    int t = threadIdx.x;
    int e0 = blockIdx.x * 4096;
    for (int i = t; i < nbuck; i += 256) hist[i] = 0;
    for (int i = 0; i < 16; ++i) {                  // single global read
        int k = i * 256 + t;
        int e = e0 + k;
        sdst[k] = (e < E) ? dst[e] : -1;
        ssrc[k] = (e < E) ? src[e] : 0;
    }
    __syncthreads();
    for (int i = 0; i < 16; ++i) {                  // pass 1: LDS histogram
        int d = sdst[i * 256 + t];
        if (d >= 0) atomicAdd(&hist[d >> BSHIFT], 1);
    }
    __syncthreads();
    for (int b = t; b < nbuck; b += 256) {          // pass 2: reserve chunks
        int c = hist[b];
        base[b] = c ? atomicAdd(&bcur[b], c) : 0;
        hist[b] = 0;
    }
    __syncthreads();
    for (int i = 0; i < 16; ++i) {                  // pass 3: grouped writes
        int k = i * 256 + t;
        int d = sdst[k];
        if (d >= 0) {
            int bk = d >> BSHIFT;
            int off = atomicAdd(&hist[bk], 1);
            ebuf[base[bk] + off] = ((unsigned)ssrc[k] << BSHIFT) | (unsigned)(d & (BSIZE - 1));
        }
    }
}

// ---- per-bucket merged: LDS stage -> hist -> scan -> deg/dinv/row_ptr
//      -> LDS-cursor scatter -> csr4 = src ----
__global__ __launch_bounds__(BSIZE) void k_bcsr(const unsigned* __restrict__ ebuf,
                                                const int* __restrict__ bcur,
                                                int* __restrict__ deg,
                                                int* __restrict__ row_ptr,
                                                float* __restrict__ dinv,
                                                unsigned* __restrict__ csr4, int n) {
    __shared__ unsigned edges[CAP];    // 64 KB
    __shared__ int hist[BSIZE];
    __shared__ int s[BSIZE];
    __shared__ int cur[BSIZE];
    int b = blockIdx.x;
    int t = threadIdx.x;
    hist[t] = 0;
    __syncthreads();
    int base = b << CAPSH;
    int cnt  = bcur[b] - base;
    int lo = b << BSHIFT;
    for (int k = t; k < cnt; k += BSIZE) {          // stage + LDS hist
        unsigned e = ebuf[base + k];
        edges[k] = e;
        atomicAdd(&hist[e & (BSIZE - 1)], 1);
    }
    __syncthreads();
    int v = hist[t];
    s[t] = v;
    __syncthreads();
    for (int off = 1; off < BSIZE; off <<= 1) {     // inclusive scan
        int add = (t >= off) ? s[t - off] : 0;
        __syncthreads();
        s[t] += add;
        __syncthreads();
    }
    int rp = base + s[t] - v;                       // padded-CSR offset
    cur[t] = rp;
    int node = lo + t;
    if (node < n) {
        deg[node]     = v;
        row_ptr[node] = rp;
        dinv[node]    = rsqrtf((float)(v + 1));
    }
    __syncthreads();
    for (int k = t; k < cnt; k += BSIZE) {          // scatter src -> csr4
        unsigned e = edges[k];
        int pos = atomicAdd(&cur[e & (BSIZE - 1)], 1);
        csr4[pos] = e >> BSHIFT;
    }
}

// ---- MFMA GEMM1: h1'[64rows,128] = dinv*(bf16(x) @ bf16(W1)) ----
// Output stored CHUNK-MAJOR: h[chunk][row][16 feats], chunk = feat>>4.
#define LDP 136
__global__ __launch_bounds__(256) void k_gemm1(const float* __restrict__ x,
                                               const short* __restrict__ w1t,
                                               const float* __restrict__ dinv,
                                               short* __restrict__ h, int nrows) {
    __shared__ short xs[64 * LDP];
    __shared__ short wt[128 * LDP];
    int t = threadIdx.x;
    int row0 = blockIdx.x * 64;
    for (int i = 0; i < 16; ++i) {
        int idx = t + i * 256;
        int r = idx >> 5, c4 = idx & 31;
        float4 v = make_float4(0.f, 0.f, 0.f, 0.f);
        if (row0 + r < nrows) v = ((const float4*)x)[(size_t)(row0 + r) * 32 + c4];
        short4 o = make_short4(f2bf(v.x), f2bf(v.y), f2bf(v.z), f2bf(v.w));
        *(short4*)&xs[r * LDP + c4 * 4] = o;
    }
    for (int i = 0; i < 16; ++i) {
        int idx = t + i * 256;
        int n = idx >> 5, c4 = idx & 31;
        *(short4*)&wt[n * LDP + c4 * 4] = ((const short4*)w1t)[idx];
    }
    __syncthreads();
    int wave = t >> 6, lane = t & 63;
    int quad = lane >> 4, c = lane & 15;
    int m0 = wave * 16;
    f32x4 acc[8] = {};
    #pragma unroll
    for (int kc = 0; kc < 4; ++kc) {
        short8v a = *(const short8v*)&xs[(m0 + c) * LDP + kc * 32 + quad * 8];
        #pragma unroll
        for (int nt = 0; nt < 8; ++nt) {
            short8v b = *(const short8v*)&wt[(nt * 16 + c) * LDP + kc * 32 + quad * 8];
            acc[nt] = __builtin_amdgcn_mfma_f32_16x16x32_bf16(a, b, acc[nt], 0, 0, 0);
        }
    }
    size_t slab = (size_t)nrows * 16;               // shorts per chunk slab
    #pragma unroll
    for (int r = 0; r < 4; ++r) {
        int row = row0 + m0 + quad * 4 + r;
        if (row < nrows) {
            float dr = dinv[row];                   // fold norm into stored row
            #pragma unroll
            for (int nt = 0; nt < 8; ++nt)
                h[(size_t)nt * slab + (size_t)row * 16 + c] = f2bf(acc[nt][r] * dr);
        }
    }
}

// ---- MFMA GEMM2: h2'[64rows,64] = dinv*(bf16(relu(aggb+b1)) @ bf16(W2)) ----
// aggb input is CHUNK-MAJOR bf16x2: aggb[chunk][row][8 pairs], chunk = pair>>3.
__global__ __launch_bounds__(256) void k_gemm2(const unsigned* __restrict__ aggb, // bf16x2
                                               const float* __restrict__ b1,
                                               const short* __restrict__ w2t,
                                               const float* __restrict__ dinv,
                                               short* __restrict__ h2, int nrows) {
    __shared__ short xs[64 * LDP];
    __shared__ short wt[64 * LDP];
    int t = threadIdx.x;
    int row0 = blockIdx.x * 64;
    size_t slab8 = (size_t)nrows * 8;                 // uints per chunk slab
    for (int i = 0; i < 16; ++i) {                    // 64 rows x 64 bf16-pairs
        int idx = t + i * 256;
        int r = idx >> 6, cp = idx & 63;
        unsigned o = 0;
        if (row0 + r < nrows) {
            unsigned u = aggb[(size_t)(cp >> 3) * slab8 + (size_t)(row0 + r) * 8 + (cp & 7)];
            float2 bb = ((const float2*)b1)[cp];
            float vx = fmaxf(bflo(u) + bb.x, 0.f);
            float vy = fmaxf(bfhi(u) + bb.y, 0.f);
            o = pack2bf(vx, vy);
        }
        *(unsigned*)&xs[r * LDP + cp * 2] = o;
    }
    for (int i = 0; i < 8; ++i) {
        int idx = t + i * 256;
        int n = idx >> 5, c4 = idx & 31;
        *(short4*)&wt[n * LDP + c4 * 4] = ((const short4*)w2t)[idx];
    }
    __syncthreads();
    int wave = t >> 6, lane = t & 63;
    int quad = lane >> 4, c = lane & 15;
    int m0 = wave * 16;
    f32x4 acc[4] = {};
    #pragma unroll
    for (int kc = 0; kc < 4; ++kc) {
        short8v av = *(const short8v*)&xs[(m0 + c) * LDP + kc * 32 + quad * 8];
        #pragma unroll
        for (int nt = 0; nt < 4; ++nt) {
            short8v b = *(const short8v*)&wt[(nt * 16 + c) * LDP + kc * 32 + quad * 8];
            acc[nt] = __builtin_amdgcn_mfma_f32_16x16x32_bf16(av, b, acc[nt], 0, 0, 0);
        }
    }
    #pragma unroll
    for (int r = 0; r < 4; ++r) {
        int row = row0 + m0 + quad * 4 + r;
        if (row < nrows) {
            float dr = dinv[row];
            #pragma unroll
            for (int nt = 0; nt < 4; ++nt)
                h2[(size_t)row * 64 + nt * 16 + c] = f2bf(acc[nt][r] * dr);
        }
    }
}

// pull 128 feats, XCD-feature-chunked:
//   aggb[c][i] = bf16( dinv[i] * (h'[c][i] + sum_nbr h'[c][s]) )
// chunk c = blockIdx&7 (pins chunk to one XCD's L2; 3.2 MB table resident).
// 8-lane groups, one node per group, 4 waves * 8 groups = 32 nodes/block.
// csr indices: one 32 B vector load per group, broadcast via __shfl.
__global__ __launch_bounds__(256) void k_pull128(const unsigned* __restrict__ h,   // bf16x2 chunk-major [8][n][8]
                                                 const int* __restrict__ row_ptr,
                                                 const int* __restrict__ deg,
                                                 const unsigned* __restrict__ csr4,
                                                 const float* __restrict__ dinv,
                                                 unsigned* __restrict__ aggb,      // bf16x2 chunk-major [8][n][8]
                                                 int n) {
    int chunk = blockIdx.x & 7;
    int nb    = blockIdx.x >> 3;
    int t = threadIdx.x;
    int lane = t & 63;
    int wv   = t >> 6;                    // 0..3
    int grp  = lane >> 3;                 // 0..7 (node group within wave)
    int sub  = lane & 7;                  // uint (bf16 pair) within 16-feat chunk
    int i = nb * 32 + wv * 8 + grp;
    if (i >= n) return;                   // whole 8-lane group exits together
    const unsigned* hc = h + (size_t)chunk * n * 8;
    float2 acc;
    {
        unsigned u = hc[(size_t)i * 8 + sub];                     // self (L2 table)
        acc.x = bflo(u);
        acc.y = bfhi(u);
    }
    int beg = __builtin_nontemporal_load(&row_ptr[i]);
    int cnt = __builtin_nontemporal_load(&deg[i]);
    int base = lane & ~7;                 // group's lane 0
    int k = 0;
    for (; k + 8 <= cnt; k += 8) {
        // 8 indices per group as one coalesced 32 B load, then broadcast
        int sidv = (int)__builtin_nontemporal_load(&csr4[beg + k + sub]);
        unsigned g[8];
        #pragma unroll
        for (int j = 0; j < 8; ++j) {
            unsigned s = (unsigned)__shfl(sidv, base + j);
            g[j] = hc[(size_t)s * 8 + sub];                       // 32 B granule, L2 hit
        }
        #pragma unroll
        for (int j = 0; j < 8; ++j) {
            acc.x += bflo(g[j]);
            acc.y += bfhi(g[j]);
        }
    }
    for (; k < cnt; ++k) {
        unsigned s = csr4[beg + k];
        unsigned g = hc[(size_t)s * 8 + sub];
        acc.x += bflo(g);
        acc.y += bfhi(g);
    }
    float di = __builtin_nontemporal_load(&dinv[i]);
    unsigned* ab = aggb + (size_t)chunk * n * 8;
    __builtin_nontemporal_store(pack2bf(acc.x * di, acc.y * di), &ab[(size_t)i * 8 + sub]);
}

// pull 64 feats: out[i] = dinv[i]*(h'[i] + sum h'[s]) + b2. One wave/node.
__global__ __launch_bounds__(256) void k_pull64(const unsigned short* __restrict__ h,
                                                const int* __restrict__ row_ptr,
                                                const int* __restrict__ deg,
                                                const unsigned* __restrict__ csr4,
                                                const float* __restrict__ dinv,
                                                const float* __restrict__ b2,
                                                float* __restrict__ out, int n) {
    int wave = (blockIdx.x * 256 + threadIdx.x) >> 6;
    int lane = threadIdx.x & 63;
    if (wave >= n) return;
    int i = __builtin_amdgcn_readfirstlane(wave);
    float acc = __uint_as_float((unsigned)h[(size_t)i * 64 + lane] << 16);  // self
    int beg = row_ptr[i];
    int cnt = deg[i];
    int k = 0;
    for (; k + 8 <= cnt; k += 8) {
        unsigned sid[8];
        unsigned short u[8];
        #pragma unroll
        for (int j = 0; j < 8; ++j) sid[j] = csr4[beg + k + j];
        #pragma unroll
        for (int j = 0; j < 8; ++j) u[j] = h[(size_t)sid[j] * 64 + lane];
        #pragma unroll
        for (int j = 0; j < 8; ++j)
            acc += __uint_as_float((unsigned)u[j] << 16);
    }
    for (; k < cnt; ++k) {
        unsigned sid = csr4[beg + k];
        acc += __uint_as_float((unsigned)h[(size_t)sid * 64 + lane] << 16);
    }
    out[(size_t)i * 64 + lane] = acc * dinv[i] + b2[lane];
}

extern "C" void kernel_launch(void* const* d_in, const int* in_sizes, int n_in,
                              void* d_out, int out_size, void* d_ws, size_t ws_size,
                              hipStream_t stream) {
    const float* x  = (const float*)d_in[0];
    const int*   ei = (const int*)d_in[1];
    const float* W1 = (const float*)d_in[2];
    const float* b1 = (const float*)d_in[3];
    const float* W2 = (const float*)d_in[4];
    const float* b2 = (const float*)d_in[5];
    float* out = (float*)d_out;

    const int N = in_sizes[0] / 128;
    const int E = in_sizes[1] / 2;
    const int* src = ei;
    const int* dst = ei + E;
    const int nbuck = (N + BSIZE - 1) >> BSHIFT;        // 196 for N=100000
    const size_t capE = (size_t)nbuck << CAPSH;         // padded edge capacity

    float* dinv     = (float*)d_ws;                     // N
    int*   deg      = (int*)(dinv + N);                 // N
    int*   row_ptr  = deg + N;                          // N
    int*   bcur     = row_ptr + N;                      // 256
    short* w1t      = (short*)(bcur + 256);             // 128*128
    short* w2t      = w1t + 128 * 128;                  // 64*128
    unsigned* csr4  = (unsigned*)(w2t + 64 * 128);      // capE (12.8 MB)
    short* bufH     = (short*)(csr4 + capE);            // N*128 bf16 (h1', chunk-major)
    short* bufH2    = bufH + (size_t)N * 128;           // N*64  bf16 (h2')
    unsigned* aggb  = (unsigned*)(bufH2 + (size_t)N * 64); // N*64 bf16x2 (agg1, chunk-major)
    unsigned* ebuf  = (unsigned*)bufH2;                 // capE uints; aliases
                                                        // bufH2+aggb (ebuf dead
                                                        // before their writes)

    const int ntile = (E + 4095) / 4096;

    // ---- weight prep + bucket cursor init ----
    k_prep<<<97, 256, 0, stream>>>(W1, W2, w1t, w2t, bcur, nbuck);

    // ---- bucketed CSR build (per-node atomics all in LDS) ----
    k_bucket<<<ntile, 256, 0, stream>>>(src, dst, bcur, ebuf, E, nbuck);
    k_bcsr<<<nbuck, BSIZE, 0, stream>>>(ebuf, bcur, deg, row_ptr, dinv, csr4, N);

    // ---- layer 1 ----
    k_gemm1<<<(N + 63) / 64, 256, 0, stream>>>(x, w1t, dinv, bufH, N);
    k_pull128<<<8 * ((N + 31) / 32), 256, 0, stream>>>((const unsigned*)bufH, row_ptr, deg, csr4, dinv, aggb, N);

    // ---- layer 2 ----
    k_gemm2<<<(N + 63) / 64, 256, 0, stream>>>(aggb, b1, w2t, dinv, bufH2, N);
    k_pull64<<<(N + 3) / 4, 256, 0, stream>>>((const unsigned short*)bufH2, row_ptr, deg, csr4, dinv, b2, out, N);
}

// Round 2
// 366.396 us; speedup vs baseline: 1.0036x; 1.0036x over previous
//
#include <hip/hip_runtime.h>
#include <hip/hip_bf16.h>

// GCN 2-layer forward, fp32 I/O. dinv folded into stored rows:
//   h1' = dinv * (x @ W1),  agg1 = dinv * (h1'[i] + sum_nbr h1'[s])
//   h2' = dinv * (relu(agg1+b1) @ W2),  out = dinv * (h2'[i] + sum h2'[s]) + b2
// so pull kernels are pure gather+add (no per-edge norm, no dinv reads).
// Packed 4B edge records; fixed-capacity bucketed CSR build with all
// per-node atomics in LDS; bf16 h/agg storage; MFMA bf16 GEMMs.
//
// Layer-1 gather (k_pull128) is XCD-feature-chunked: h1'/aggb stored
// chunk-major [8][N][16 feats]; chunk = blockIdx&7 pins each 3.2 MB slab
// to one XCD's 4 MB L2 (random gather -> L2 hit, ~17x reuse).
// THIS ROUND: CSR rows padded to 16B alignment so index loads are
// group-uniform dwordx4 vector loads (no __shfl in the critical path);
// 16 gathers in flight per k-step; scalar tail replaced by a single
// predicated 16-wide step (clamp index to self row, cndmask value to 0).
// Same vector-index + predicated-tail treatment in k_pull64.
// Pipeline:
//  1) k_prep: W1,W2 -> bf16 transposed; bcur[b] = b*CAP
//  2) k_bucket: partition packed {src,dloc} by dst>>9 into ebuf
//  3) k_bcsr:  per-bucket LDS stage -> hist -> scan (16B-padded rows)
//              -> deg/dinv/row_ptr -> LDS-cursor scatter -> csr4 = src
//  4) h1' = dinv*(x @ W1) -> bf16 chunk-major     (k_gemm1, MFMA)
//  5) aggb = dinv*(self+gather-sum of h1') -> bf16 chunk-major (k_pull128)
//  6) h2' = dinv*(relu(aggb+b1) @ W2) -> bf16 row-major (k_gemm2, MFMA)
//  7) out = dinv*(self+gather-sum of h2') + b2    (k_pull64)

typedef short short8v __attribute__((ext_vector_type(8)));   // 8 bf16 (4 VGPRs)
typedef float f32x4   __attribute__((ext_vector_type(4)));   // MFMA acc
typedef int   int4v   __attribute__((ext_vector_type(4)));   // dwordx4 index load

#define BSHIFT 9           // bucket = dst >> 9 (span 512 nodes)
#define BSIZE  512
#define CAPSH  14          // per-bucket capacity 16384 (padded mean ~9.7K, >40 sigma)
#define CAP    (1 << CAPSH)

// RNE fp32 -> bf16 (finite inputs)
__device__ __forceinline__ short f2bf(float f) {
    unsigned u = __float_as_uint(f);
    return (short)((u + 0x7fffu + ((u >> 16) & 1u)) >> 16);
}
__device__ __forceinline__ unsigned pack2bf(float a, float b) {
    return (unsigned)(unsigned short)f2bf(a) | ((unsigned)(unsigned short)f2bf(b) << 16);
}
__device__ __forceinline__ float bflo(unsigned u) { return __uint_as_float(u << 16); }
__device__ __forceinline__ float bfhi(unsigned u) { return __uint_as_float(u & 0xffff0000u); }

// ---- W prep + bucket-cursor init (one launch) ----
__global__ void k_prep(const float* __restrict__ W1, const float* __restrict__ W2,
                       short* __restrict__ w1t, short* __restrict__ w2t,
                       int* __restrict__ bcur, int nbuck) {
    int b = blockIdx.x;
    int t = threadIdx.x;
    if (b == gridDim.x - 1) {                 // last block: init bucket cursors
        if (t < nbuck) bcur[t] = t << CAPSH;
        return;
    }
    int i = b * 256 + t;                      // 96 blocks cover 24576 elems
    if (i < 128 * 128) {
        int n = i >> 7, k = i & 127;
        w1t[i] = f2bf(W1[k * 128 + n]);
    } else {
        int j = i - 128 * 128;
        int n = j >> 7, k = j & 127;
        w2t[j] = f2bf(W2[k * 64 + n]);
    }
}

// ---- partition edges into packed ebuf: entry = (src<<9) | (dst&511) ----
__global__ __launch_bounds__(256) void k_bucket(const int* __restrict__ src,
                                                const int* __restrict__ dst,
                                                int* __restrict__ bcur,
                                                unsigned* __restrict__ ebuf,
                                                int E, int nbuck) {
    __shared__ int sdst[4096];
    __shared__ int ssrc[4096];
    __shared__ int hist[256];
    __shared__ int base[256];
    int t = threadIdx.x;
    int e0 = blockIdx.x * 4096;
    for (int i = t; i < nbuck; i += 256) hist[i] = 0;
    for (int i = 0; i < 16; ++i) {                  // single global read
        int k = i * 256 + t;
        int e = e0 + k;
        sdst[k] = (e < E) ? dst[e] : -1;
        ssrc[k] = (e < E) ? src[e] : 0;
    }
    __syncthreads();
    for (int i = 0; i < 16; ++i) {                  // pass 1: LDS histogram
        int d = sdst[i * 256 + t];
        if (d >= 0) atomicAdd(&hist[d >> BSHIFT], 1);
    }
    __syncthreads();
    for (int b = t; b < nbuck; b += 256) {          // pass 2: reserve chunks
        int c = hist[b];
        base[b] = c ? atomicAdd(&bcur[b], c) : 0;
        hist[b] = 0;
    }
    __syncthreads();
    for (int i = 0; i < 16; ++i) {                  // pass 3: grouped writes
        int k = i * 256 + t;
        int d = sdst[k];
        if (d >= 0) {
            int bk = d >> BSHIFT;
            int off = atomicAdd(&hist[bk], 1);
            ebuf[base[bk] + off] = ((unsigned)ssrc[k] << BSHIFT) | (unsigned)(d & (BSIZE - 1));
        }
    }
}

// ---- per-bucket merged: LDS stage -> hist -> scan (rows padded to 4
//      entries = 16B so index loads can be dwordx4) -> deg/dinv/row_ptr
//      -> LDS-cursor scatter -> csr4 = src ----
__global__ __launch_bounds__(BSIZE) void k_bcsr(const unsigned* __restrict__ ebuf,
                                                const int* __restrict__ bcur,
                                                int* __restrict__ deg,
                                                int* __restrict__ row_ptr,
                                                float* __restrict__ dinv,
                                                unsigned* __restrict__ csr4, int n) {
    __shared__ unsigned edges[CAP];    // 64 KB
    __shared__ int hist[BSIZE];
    __shared__ int s[BSIZE];
    __shared__ int cur[BSIZE];
    int b = blockIdx.x;
    int t = threadIdx.x;
    hist[t] = 0;
    __syncthreads();
    int base = b << CAPSH;
    int cnt  = bcur[b] - base;
    int lo = b << BSHIFT;
    for (int k = t; k < cnt; k += BSIZE) {          // stage + LDS hist
        unsigned e = ebuf[base + k];
        edges[k] = e;
        atomicAdd(&hist[e & (BSIZE - 1)], 1);
    }
    __syncthreads();
    int v = hist[t];
    int pv = (v + 3) & ~3;                          // 16B-aligned row span
    s[t] = pv;
    __syncthreads();
    for (int off = 1; off < BSIZE; off <<= 1) {     // inclusive scan of padded
        int add = (t >= off) ? s[t - off] : 0;
        __syncthreads();
        s[t] += add;
        __syncthreads();
    }
    int rp = base + s[t] - pv;                      // padded-CSR offset (16B aligned)
    cur[t] = rp;
    int node = lo + t;
    if (node < n) {
        deg[node]     = v;
        row_ptr[node] = rp;
        dinv[node]    = rsqrtf((float)(v + 1));
    }
    __syncthreads();
    for (int k = t; k < cnt; k += BSIZE) {          // scatter src -> csr4
        unsigned e = edges[k];
        int pos = atomicAdd(&cur[e & (BSIZE - 1)], 1);
        csr4[pos] = e >> BSHIFT;
    }
}

// ---- MFMA GEMM1: h1'[64rows,128] = dinv*(bf16(x) @ bf16(W1)) ----
// Output stored CHUNK-MAJOR: h[chunk][row][16 feats], chunk = feat>>4.
#define LDP 136
__global__ __launch_bounds__(256) void k_gemm1(const float* __restrict__ x,
                                               const short* __restrict__ w1t,
                                               const float* __restrict__ dinv,
                                               short* __restrict__ h, int nrows) {
    __shared__ short xs[64 * LDP];
    __shared__ short wt[128 * LDP];
    int t = threadIdx.x;
    int row0 = blockIdx.x * 64;
    for (int i = 0; i < 16; ++i) {
        int idx = t + i * 256;
        int r = idx >> 5, c4 = idx & 31;
        float4 v = make_float4(0.f, 0.f, 0.f, 0.f);
        if (row0 + r < nrows) v = ((const float4*)x)[(size_t)(row0 + r) * 32 + c4];
        short4 o = make_short4(f2bf(v.x), f2bf(v.y), f2bf(v.z), f2bf(v.w));
        *(short4*)&xs[r * LDP + c4 * 4] = o;
    }
    for (int i = 0; i < 16; ++i) {
        int idx = t + i * 256;
        int n = idx >> 5, c4 = idx & 31;
        *(short4*)&wt[n * LDP + c4 * 4] = ((const short4*)w1t)[idx];
    }
    __syncthreads();
    int wave = t >> 6, lane = t & 63;
    int quad = lane >> 4, c = lane & 15;
    int m0 = wave * 16;
    f32x4 acc[8] = {};
    #pragma unroll
    for (int kc = 0; kc < 4; ++kc) {
        short8v a = *(const short8v*)&xs[(m0 + c) * LDP + kc * 32 + quad * 8];
        #pragma unroll
        for (int nt = 0; nt < 8; ++nt) {
            short8v b = *(const short8v*)&wt[(nt * 16 + c) * LDP + kc * 32 + quad * 8];
            acc[nt] = __builtin_amdgcn_mfma_f32_16x16x32_bf16(a, b, acc[nt], 0, 0, 0);
        }
    }
    size_t slab = (size_t)nrows * 16;               // shorts per chunk slab
    #pragma unroll
    for (int r = 0; r < 4; ++r) {
        int row = row0 + m0 + quad * 4 + r;
        if (row < nrows) {
            float dr = dinv[row];                   // fold norm into stored row
            #pragma unroll
            for (int nt = 0; nt < 8; ++nt)
                h[(size_t)nt * slab + (size_t)row * 16 + c] = f2bf(acc[nt][r] * dr);
        }
    }
}

// ---- MFMA GEMM2: h2'[64rows,64] = dinv*(bf16(relu(aggb+b1)) @ bf16(W2)) ----
// aggb input is CHUNK-MAJOR bf16x2: aggb[chunk][row][8 pairs], chunk = pair>>3.
__global__ __launch_bounds__(256) void k_gemm2(const unsigned* __restrict__ aggb, // bf16x2
                                               const float* __restrict__ b1,
                                               const short* __restrict__ w2t,
                                               const float* __restrict__ dinv,
                                               short* __restrict__ h2, int nrows) {
    __shared__ short xs[64 * LDP];
    __shared__ short wt[64 * LDP];
    int t = threadIdx.x;
    int row0 = blockIdx.x * 64;
    size_t slab8 = (size_t)nrows * 8;                 // uints per chunk slab
    for (int i = 0; i < 16; ++i) {                    // 64 rows x 64 bf16-pairs
        int idx = t + i * 256;
        int r = idx >> 6, cp = idx & 63;
        unsigned o = 0;
        if (row0 + r < nrows) {
            unsigned u = aggb[(size_t)(cp >> 3) * slab8 + (size_t)(row0 + r) * 8 + (cp & 7)];
            float2 bb = ((const float2*)b1)[cp];
            float vx = fmaxf(bflo(u) + bb.x, 0.f);
            float vy = fmaxf(bfhi(u) + bb.y, 0.f);
            o = pack2bf(vx, vy);
        }
        *(unsigned*)&xs[r * LDP + cp * 2] = o;
    }
    for (int i = 0; i < 8; ++i) {
        int idx = t + i * 256;
        int n = idx >> 5, c4 = idx & 31;
        *(short4*)&wt[n * LDP + c4 * 4] = ((const short4*)w2t)[idx];
    }
    __syncthreads();
    int wave = t >> 6, lane = t & 63;
    int quad = lane >> 4, c = lane & 15;
    int m0 = wave * 16;
    f32x4 acc[4] = {};
    #pragma unroll
    for (int kc = 0; kc < 4; ++kc) {
        short8v av = *(const short8v*)&xs[(m0 + c) * LDP + kc * 32 + quad * 8];
        #pragma unroll
        for (int nt = 0; nt < 4; ++nt) {
            short8v b = *(const short8v*)&wt[(nt * 16 + c) * LDP + kc * 32 + quad * 8];
            acc[nt] = __builtin_amdgcn_mfma_f32_16x16x32_bf16(av, b, acc[nt], 0, 0, 0);
        }
    }
    #pragma unroll
    for (int r = 0; r < 4; ++r) {
        int row = row0 + m0 + quad * 4 + r;
        if (row < nrows) {
            float dr = dinv[row];
            #pragma unroll
            for (int nt = 0; nt < 4; ++nt)
                h2[(size_t)row * 64 + nt * 16 + c] = f2bf(acc[nt][r] * dr);
        }
    }
}

// pull 128 feats, XCD-feature-chunked:
//   aggb[c][i] = bf16( dinv[i] * (h'[c][i] + sum_nbr h'[c][s]) )
// chunk c = blockIdx&7 (pins 3.2 MB slab to one XCD's L2).
// 8-lane groups, one node per group; indices via group-uniform dwordx4
// loads (rows are 16B-aligned), 16 gathers in flight per k-step; tail is
// one predicated 16-wide step (clamp index to self, cndmask value to 0).
__global__ __launch_bounds__(256) void k_pull128(const unsigned* __restrict__ h,   // bf16x2 chunk-major [8][n][8]
                                                 const int* __restrict__ row_ptr,
                                                 const int* __restrict__ deg,
                                                 const unsigned* __restrict__ csr4,
                                                 const float* __restrict__ dinv,
                                                 unsigned* __restrict__ aggb,      // bf16x2 chunk-major [8][n][8]
                                                 int n) {
    int chunk = blockIdx.x & 7;
    int nb    = blockIdx.x >> 3;
    int t = threadIdx.x;
    int lane = t & 63;
    int wv   = t >> 6;                    // 0..3
    int grp  = lane >> 3;                 // 0..7 (node group within wave)
    int sub  = lane & 7;                  // uint (bf16 pair) within 16-feat chunk
    int i = nb * 32 + wv * 8 + grp;
    if (i >= n) return;                   // whole 8-lane group exits together
    const unsigned* hc = h + (size_t)chunk * ((size_t)n * 8);
    float ax, ay;
    {
        unsigned u = hc[(size_t)i * 8 + sub];                     // self (L2 table)
        ax = bflo(u);
        ay = bfhi(u);
    }
    int beg = __builtin_nontemporal_load(&row_ptr[i]);            // 16B aligned
    int cnt = __builtin_nontemporal_load(&deg[i]);
    int k = 0;
    for (; k + 16 <= cnt; k += 16) {
        const int4v* p = (const int4v*)(csr4 + beg + k);
        int4v s0 = __builtin_nontemporal_load(p);
        int4v s1 = __builtin_nontemporal_load(p + 1);
        int4v s2 = __builtin_nontemporal_load(p + 2);
        int4v s3 = __builtin_nontemporal_load(p + 3);
        unsigned g[16];
        #pragma unroll
        for (int j = 0; j < 4; ++j) {
            g[j]      = hc[(size_t)(unsigned)s0[j] * 8 + sub];
            g[4 + j]  = hc[(size_t)(unsigned)s1[j] * 8 + sub];
            g[8 + j]  = hc[(size_t)(unsigned)s2[j] * 8 + sub];
            g[12 + j] = hc[(size_t)(unsigned)s3[j] * 8 + sub];
        }
        #pragma unroll
        for (int j = 0; j < 16; ++j) {
            ax += bflo(g[j]);
            ay += bfhi(g[j]);
        }
    }
    if (k < cnt) {                        // predicated tail (<=15 edges)
        const int4v* p = (const int4v*)(csr4 + beg + k);
        int4v s0 = __builtin_nontemporal_load(p);
        int4v s1 = __builtin_nontemporal_load(p + 1);
        int4v s2 = __builtin_nontemporal_load(p + 2);
        int4v s3 = __builtin_nontemporal_load(p + 3);
        int sv[16];
        #pragma unroll
        for (int j = 0; j < 4; ++j) {
            sv[j] = s0[j]; sv[4 + j] = s1[j]; sv[8 + j] = s2[j]; sv[12 + j] = s3[j];
        }
        #pragma unroll
        for (int j = 0; j < 16; ++j) {
            bool ok = (k + j) < cnt;
            unsigned s = ok ? (unsigned)sv[j] : (unsigned)i;      // clamp to valid row
            unsigned gg = hc[(size_t)s * 8 + sub];
            gg = ok ? gg : 0u;                                    // zero contribution
            ax += bflo(gg);
            ay += bfhi(gg);
        }
    }
    float di = __builtin_nontemporal_load(&dinv[i]);
    unsigned* ab = aggb + (size_t)chunk * ((size_t)n * 8);
    __builtin_nontemporal_store(pack2bf(ax * di, ay * di), &ab[(size_t)i * 8 + sub]);
}

// pull 64 feats: out[i] = dinv[i]*(h'[i] + sum h'[s]) + b2. One wave/node.
// dwordx4 index loads (16B-aligned rows) + predicated 8-wide tail.
__global__ __launch_bounds__(256) void k_pull64(const unsigned short* __restrict__ h,
                                                const int* __restrict__ row_ptr,
                                                const int* __restrict__ deg,
                                                const unsigned* __restrict__ csr4,
                                                const float* __restrict__ dinv,
                                                const float* __restrict__ b2,
                                                float* __restrict__ out, int n) {
    int wave = (blockIdx.x * 256 + threadIdx.x) >> 6;
    int lane = threadIdx.x & 63;
    if (wave >= n) return;
    int i = __builtin_amdgcn_readfirstlane(wave);
    float acc = __uint_as_float((unsigned)h[(size_t)i * 64 + lane] << 16);  // self
    int beg = __builtin_nontemporal_load(&row_ptr[i]);
    int cnt = __builtin_nontemporal_load(&deg[i]);
    int k = 0;
    for (; k + 8 <= cnt; k += 8) {
        const int4v* p = (const int4v*)(csr4 + beg + k);
        int4v s0 = __builtin_nontemporal_load(p);
        int4v s1 = __builtin_nontemporal_load(p + 1);
        unsigned short u[8];
        #pragma unroll
        for (int j = 0; j < 4; ++j) {
            u[j]     = h[(size_t)(unsigned)s0[j] * 64 + lane];
            u[4 + j] = h[(size_t)(unsigned)s1[j] * 64 + lane];
        }
        #pragma unroll
        for (int j = 0; j < 8; ++j)
            acc += __uint_as_float((unsigned)u[j] << 16);
    }
    if (k < cnt) {                        // predicated tail (<=7 edges)
        const int4v* p = (const int4v*)(csr4 + beg + k);
        int4v s0 = __builtin_nontemporal_load(p);
        int4v s1 = __builtin_nontemporal_load(p + 1);
        int sv[8];
        #pragma unroll
        for (int j = 0; j < 4; ++j) { sv[j] = s0[j]; sv[4 + j] = s1[j]; }
        #pragma unroll
        for (int j = 0; j < 8; ++j) {
            bool ok = (k + j) < cnt;
            unsigned s = ok ? (unsigned)sv[j] : (unsigned)i;
            unsigned uu = (unsigned)h[(size_t)s * 64 + lane] << 16;
            acc += ok ? __uint_as_float(uu) : 0.f;
        }
    }
    out[(size_t)i * 64 + lane] = acc * dinv[i] + b2[lane];
}

extern "C" void kernel_launch(void* const* d_in, const int* in_sizes, int n_in,
                              void* d_out, int out_size, void* d_ws, size_t ws_size,
                              hipStream_t stream) {
    const float* x  = (const float*)d_in[0];
    const int*   ei = (const int*)d_in[1];
    const float* W1 = (const float*)d_in[2];
    const float* b1 = (const float*)d_in[3];
    const float* W2 = (const float*)d_in[4];
    const float* b2 = (const float*)d_in[5];
    float* out = (float*)d_out;

    const int N = in_sizes[0] / 128;
    const int E = in_sizes[1] / 2;
    const int* src = ei;
    const int* dst = ei + E;
    const int nbuck = (N + BSIZE - 1) >> BSHIFT;        // 196 for N=100000
    const size_t capE = (size_t)nbuck << CAPSH;         // padded edge capacity

    float* dinv     = (float*)d_ws;                     // N
    int*   deg      = (int*)(dinv + N);                 // N
    int*   row_ptr  = deg + N;                          // N
    int*   bcur     = row_ptr + N;                      // 256
    short* w1t      = (short*)(bcur + 256);             // 128*128
    short* w2t      = w1t + 128 * 128;                  // 64*128
    unsigned* csr4  = (unsigned*)(w2t + 64 * 128);      // capE (12.8 MB)
    short* bufH     = (short*)(csr4 + capE);            // N*128 bf16 (h1', chunk-major)
    short* bufH2    = bufH + (size_t)N * 128;           // N*64  bf16 (h2')
    unsigned* aggb  = (unsigned*)(bufH2 + (size_t)N * 64); // N*64 bf16x2 (agg1, chunk-major)
    unsigned* ebuf  = (unsigned*)bufH2;                 // capE uints; aliases
                                                        // bufH2+aggb (ebuf dead
                                                        // before their writes)

    const int ntile = (E + 4095) / 4096;

    // ---- weight prep + bucket cursor init ----
    k_prep<<<97, 256, 0, stream>>>(W1, W2, w1t, w2t, bcur, nbuck);

    // ---- bucketed CSR build (per-node atomics all in LDS) ----
    k_bucket<<<ntile, 256, 0, stream>>>(src, dst, bcur, ebuf, E, nbuck);
    k_bcsr<<<nbuck, BSIZE, 0, stream>>>(ebuf, bcur, deg, row_ptr, dinv, csr4, N);

    // ---- layer 1 ----
    k_gemm1<<<(N + 63) / 64, 256, 0, stream>>>(x, w1t, dinv, bufH, N);
    k_pull128<<<8 * ((N + 31) / 32), 256, 0, stream>>>((const unsigned*)bufH, row_ptr, deg, csr4, dinv, aggb, N);

    // ---- layer 2 ----
    k_gemm2<<<(N + 63) / 64, 256, 0, stream>>>(aggb, b1, w2t, dinv, bufH2, N);
    k_pull64<<<(N + 3) / 4, 256, 0, stream>>>((const unsigned short*)bufH2, row_ptr, deg, csr4, dinv, b2, out, N);
}

// Round 3
// 325.359 us; speedup vs baseline: 1.1302x; 1.1261x over previous
//
#include <hip/hip_runtime.h>
#include <hip/hip_bf16.h>

// GCN 2-layer forward, fp32 I/O. dinv folded into stored rows:
//   h1' = dinv * (x @ W1),  agg1 = dinv * (h1'[i] + sum_nbr h1'[s])
//   h2' = dinv * (relu(agg1+b1) @ W2),  out = dinv * (h2'[i] + sum h2'[s]) + b2
// so pull kernels are pure gather+add (no per-edge norm, no dinv reads).
// Packed 4B edge records; fixed-capacity bucketed CSR build with all
// per-node atomics in LDS; bf16 h/agg storage; MFMA bf16 GEMMs.
//
// Layer-1 gather (k_pull128) is XCD-feature-chunked: h1'/aggb stored
// chunk-major [8][N][16 feats]; chunk = blockIdx&7 pins each 3.2 MB slab
// to one XCD's 4 MB L2 (random gather -> L2 hit).
// THIS ROUND: block-level LDS index staging. A block's 32 nodes have
// contiguous 16B-padded CSR rows, so the whole index range (~600 entries)
// is bulk-loaded into LDS with coalesced NT dwordx4 reads up front. The
// gather loop reads indices from LDS (broadcast) -> no global idx loads
// in the dependent chain, ~4x fewer TA line-requests for indices.
// dinv recomputed as rsqrtf(deg+1) (bit-identical to k_bcsr's).
// Pipeline:
//  1) k_prep: W1,W2 -> bf16 transposed; bcur[b] = b*CAP
//  2) k_bucket: partition packed {src,dloc} by dst>>9 into ebuf
//  3) k_bcsr:  per-bucket LDS stage -> hist -> scan (16B-padded rows)
//              -> deg/dinv/row_ptr -> LDS-cursor scatter -> csr4 = src
//  4) h1' = dinv*(x @ W1) -> bf16 chunk-major     (k_gemm1, MFMA)
//  5) aggb = dinv*(self+gather-sum of h1') -> bf16 chunk-major (k_pull128)
//  6) h2' = dinv*(relu(aggb+b1) @ W2) -> bf16 row-major (k_gemm2, MFMA)
//  7) out = dinv*(self+gather-sum of h2') + b2    (k_pull64)

typedef short short8v __attribute__((ext_vector_type(8)));   // 8 bf16 (4 VGPRs)
typedef float f32x4   __attribute__((ext_vector_type(4)));   // MFMA acc
typedef int   int4v   __attribute__((ext_vector_type(4)));   // dwordx4 index load

#define BSHIFT 9           // bucket = dst >> 9 (span 512 nodes)
#define BSIZE  512
#define CAPSH  14          // per-bucket capacity 16384 (padded mean ~9.7K, >40 sigma)
#define CAP    (1 << CAPSH)
#define IDXCAP 2080        // staged-index LDS capacity (fast path: range <= 2048)

// RNE fp32 -> bf16 (finite inputs)
__device__ __forceinline__ short f2bf(float f) {
    unsigned u = __float_as_uint(f);
    return (short)((u + 0x7fffu + ((u >> 16) & 1u)) >> 16);
}
__device__ __forceinline__ unsigned pack2bf(float a, float b) {
    return (unsigned)(unsigned short)f2bf(a) | ((unsigned)(unsigned short)f2bf(b) << 16);
}
__device__ __forceinline__ float bflo(unsigned u) { return __uint_as_float(u << 16); }
__device__ __forceinline__ float bfhi(unsigned u) { return __uint_as_float(u & 0xffff0000u); }

// ---- W prep + bucket-cursor init (one launch) ----
__global__ void k_prep(const float* __restrict__ W1, const float* __restrict__ W2,
                       short* __restrict__ w1t, short* __restrict__ w2t,
                       int* __restrict__ bcur, int nbuck) {
    int b = blockIdx.x;
    int t = threadIdx.x;
    if (b == gridDim.x - 1) {                 // last block: init bucket cursors
        if (t < nbuck) bcur[t] = t << CAPSH;
        return;
    }
    int i = b * 256 + t;                      // 96 blocks cover 24576 elems
    if (i < 128 * 128) {
        int n = i >> 7, k = i & 127;
        w1t[i] = f2bf(W1[k * 128 + n]);
    } else {
        int j = i - 128 * 128;
        int n = j >> 7, k = j & 127;
        w2t[j] = f2bf(W2[k * 64 + n]);
    }
}

// ---- partition edges into packed ebuf: entry = (src<<9) | (dst&511) ----
__global__ __launch_bounds__(256) void k_bucket(const int* __restrict__ src,
                                                const int* __restrict__ dst,
                                                int* __restrict__ bcur,
                                                unsigned* __restrict__ ebuf,
                                                int E, int nbuck) {
    __shared__ int sdst[4096];
    __shared__ int ssrc[4096];
    __shared__ int hist[256];
    __shared__ int base[256];
    int t = threadIdx.x;
    int e0 = blockIdx.x * 4096;
    for (int i = t; i < nbuck; i += 256) hist[i] = 0;
    for (int i = 0; i < 16; ++i) {                  // single global read
        int k = i * 256 + t;
        int e = e0 + k;
        sdst[k] = (e < E) ? dst[e] : -1;
        ssrc[k] = (e < E) ? src[e] : 0;
    }
    __syncthreads();
    for (int i = 0; i < 16; ++i) {                  // pass 1: LDS histogram
        int d = sdst[i * 256 + t];
        if (d >= 0) atomicAdd(&hist[d >> BSHIFT], 1);
    }
    __syncthreads();
    for (int b = t; b < nbuck; b += 256) {          // pass 2: reserve chunks
        int c = hist[b];
        base[b] = c ? atomicAdd(&bcur[b], c) : 0;
        hist[b] = 0;
    }
    __syncthreads();
    for (int i = 0; i < 16; ++i) {                  // pass 3: grouped writes
        int k = i * 256 + t;
        int d = sdst[k];
        if (d >= 0) {
            int bk = d >> BSHIFT;
            int off = atomicAdd(&hist[bk], 1);
            ebuf[base[bk] + off] = ((unsigned)ssrc[k] << BSHIFT) | (unsigned)(d & (BSIZE - 1));
        }
    }
}

// ---- per-bucket merged: LDS stage -> hist -> scan (rows padded to 4
//      entries = 16B so index loads can be dwordx4) -> deg/dinv/row_ptr
//      -> LDS-cursor scatter -> csr4 = src ----
__global__ __launch_bounds__(BSIZE) void k_bcsr(const unsigned* __restrict__ ebuf,
                                                const int* __restrict__ bcur,
                                                int* __restrict__ deg,
                                                int* __restrict__ row_ptr,
                                                float* __restrict__ dinv,
                                                unsigned* __restrict__ csr4, int n) {
    __shared__ unsigned edges[CAP];    // 64 KB
    __shared__ int hist[BSIZE];
    __shared__ int s[BSIZE];
    __shared__ int cur[BSIZE];
    int b = blockIdx.x;
    int t = threadIdx.x;
    hist[t] = 0;
    __syncthreads();
    int base = b << CAPSH;
    int cnt  = bcur[b] - base;
    int lo = b << BSHIFT;
    for (int k = t; k < cnt; k += BSIZE) {          // stage + LDS hist
        unsigned e = ebuf[base + k];
        edges[k] = e;
        atomicAdd(&hist[e & (BSIZE - 1)], 1);
    }
    __syncthreads();
    int v = hist[t];
    int pv = (v + 3) & ~3;                          // 16B-aligned row span
    s[t] = pv;
    __syncthreads();
    for (int off = 1; off < BSIZE; off <<= 1) {     // inclusive scan of padded
        int add = (t >= off) ? s[t - off] : 0;
        __syncthreads();
        s[t] += add;
        __syncthreads();
    }
    int rp = base + s[t] - pv;                      // padded-CSR offset (16B aligned)
    cur[t] = rp;
    int node = lo + t;
    if (node < n) {
        deg[node]     = v;
        row_ptr[node] = rp;
        dinv[node]    = rsqrtf((float)(v + 1));
    }
    __syncthreads();
    for (int k = t; k < cnt; k += BSIZE) {          // scatter src -> csr4
        unsigned e = edges[k];
        int pos = atomicAdd(&cur[e & (BSIZE - 1)], 1);
        csr4[pos] = e >> BSHIFT;
    }
}

// ---- MFMA GEMM1: h1'[64rows,128] = dinv*(bf16(x) @ bf16(W1)) ----
// Output stored CHUNK-MAJOR: h[chunk][row][16 feats], chunk = feat>>4.
#define LDP 136
__global__ __launch_bounds__(256) void k_gemm1(const float* __restrict__ x,
                                               const short* __restrict__ w1t,
                                               const float* __restrict__ dinv,
                                               short* __restrict__ h, int nrows) {
    __shared__ short xs[64 * LDP];
    __shared__ short wt[128 * LDP];
    int t = threadIdx.x;
    int row0 = blockIdx.x * 64;
    for (int i = 0; i < 16; ++i) {
        int idx = t + i * 256;
        int r = idx >> 5, c4 = idx & 31;
        float4 v = make_float4(0.f, 0.f, 0.f, 0.f);
        if (row0 + r < nrows) v = ((const float4*)x)[(size_t)(row0 + r) * 32 + c4];
        short4 o = make_short4(f2bf(v.x), f2bf(v.y), f2bf(v.z), f2bf(v.w));
        *(short4*)&xs[r * LDP + c4 * 4] = o;
    }
    for (int i = 0; i < 16; ++i) {
        int idx = t + i * 256;
        int n = idx >> 5, c4 = idx & 31;
        *(short4*)&wt[n * LDP + c4 * 4] = ((const short4*)w1t)[idx];
    }
    __syncthreads();
    int wave = t >> 6, lane = t & 63;
    int quad = lane >> 4, c = lane & 15;
    int m0 = wave * 16;
    f32x4 acc[8] = {};
    #pragma unroll
    for (int kc = 0; kc < 4; ++kc) {
        short8v a = *(const short8v*)&xs[(m0 + c) * LDP + kc * 32 + quad * 8];
        #pragma unroll
        for (int nt = 0; nt < 8; ++nt) {
            short8v b = *(const short8v*)&wt[(nt * 16 + c) * LDP + kc * 32 + quad * 8];
            acc[nt] = __builtin_amdgcn_mfma_f32_16x16x32_bf16(a, b, acc[nt], 0, 0, 0);
        }
    }
    size_t slab = (size_t)nrows * 16;               // shorts per chunk slab
    #pragma unroll
    for (int r = 0; r < 4; ++r) {
        int row = row0 + m0 + quad * 4 + r;
        if (row < nrows) {
            float dr = dinv[row];                   // fold norm into stored row
            #pragma unroll
            for (int nt = 0; nt < 8; ++nt)
                h[(size_t)nt * slab + (size_t)row * 16 + c] = f2bf(acc[nt][r] * dr);
        }
    }
}

// ---- MFMA GEMM2: h2'[64rows,64] = dinv*(bf16(relu(aggb+b1)) @ bf16(W2)) ----
// aggb input is CHUNK-MAJOR bf16x2: aggb[chunk][row][8 pairs], chunk = pair>>3.
__global__ __launch_bounds__(256) void k_gemm2(const unsigned* __restrict__ aggb, // bf16x2
                                               const float* __restrict__ b1,
                                               const short* __restrict__ w2t,
                                               const float* __restrict__ dinv,
                                               short* __restrict__ h2, int nrows) {
    __shared__ short xs[64 * LDP];
    __shared__ short wt[64 * LDP];
    int t = threadIdx.x;
    int row0 = blockIdx.x * 64;
    size_t slab8 = (size_t)nrows * 8;                 // uints per chunk slab
    for (int i = 0; i < 16; ++i) {                    // 64 rows x 64 bf16-pairs
        int idx = t + i * 256;
        int r = idx >> 6, cp = idx & 63;
        unsigned o = 0;
        if (row0 + r < nrows) {
            unsigned u = aggb[(size_t)(cp >> 3) * slab8 + (size_t)(row0 + r) * 8 + (cp & 7)];
            float2 bb = ((const float2*)b1)[cp];
            float vx = fmaxf(bflo(u) + bb.x, 0.f);
            float vy = fmaxf(bfhi(u) + bb.y, 0.f);
            o = pack2bf(vx, vy);
        }
        *(unsigned*)&xs[r * LDP + cp * 2] = o;
    }
    for (int i = 0; i < 8; ++i) {
        int idx = t + i * 256;
        int n = idx >> 5, c4 = idx & 31;
        *(short4*)&wt[n * LDP + c4 * 4] = ((const short4*)w2t)[idx];
    }
    __syncthreads();
    int wave = t >> 6, lane = t & 63;
    int quad = lane >> 4, c = lane & 15;
    int m0 = wave * 16;
    f32x4 acc[4] = {};
    #pragma unroll
    for (int kc = 0; kc < 4; ++kc) {
        short8v av = *(const short8v*)&xs[(m0 + c) * LDP + kc * 32 + quad * 8];
        #pragma unroll
        for (int nt = 0; nt < 4; ++nt) {
            short8v b = *(const short8v*)&wt[(nt * 16 + c) * LDP + kc * 32 + quad * 8];
            acc[nt] = __builtin_amdgcn_mfma_f32_16x16x32_bf16(av, b, acc[nt], 0, 0, 0);
        }
    }
    #pragma unroll
    for (int r = 0; r < 4; ++r) {
        int row = row0 + m0 + quad * 4 + r;
        if (row < nrows) {
            float dr = dinv[row];
            #pragma unroll
            for (int nt = 0; nt < 4; ++nt)
                h2[(size_t)row * 64 + nt * 16 + c] = f2bf(acc[nt][r] * dr);
        }
    }
}

// pull 128 feats, XCD-feature-chunked + LDS-staged indices:
//   aggb[c][i] = bf16( dinv[i] * (h'[c][i] + sum_nbr h'[c][s]) )
// chunk c = blockIdx&7 (pins 3.2 MB slab to one XCD's L2).
// Block = 32 consecutive nodes; their padded CSR rows are contiguous, so
// the whole index range is staged into LDS with coalesced NT dwordx4
// loads. Gather loop: indices from LDS (broadcast), 16 independent L2
// gathers in flight, no global loads in the dependent chain.
__global__ __launch_bounds__(256) void k_pull128(const unsigned* __restrict__ h,   // bf16x2 chunk-major [8][n][8]
                                                 const int* __restrict__ row_ptr,
                                                 const int* __restrict__ deg,
                                                 const unsigned* __restrict__ csr4,
                                                 unsigned* __restrict__ aggb,      // bf16x2 chunk-major [8][n][8]
                                                 int n) {
    __shared__ int sIdx[IDXCAP];
    __shared__ int sRP[32];
    __shared__ int sDG[32];
    int chunk = blockIdx.x & 7;
    int nb    = blockIdx.x >> 3;
    int i0 = nb * 32;
    int t = threadIdx.x;
    if (t < 32) {                          // stage row info for the 32 nodes
        int node = i0 + t;
        int rp = 0, dg = 0;
        if (node < n) {
            rp = __builtin_nontemporal_load(&row_ptr[node]);
            dg = __builtin_nontemporal_load(&deg[node]);
        }
        sRP[t] = rp;
        sDG[t] = dg;
    }
    __syncthreads();
    int rpBeg = sRP[0];
    int lastLocal = min(31, n - 1 - i0);   // i0 < n by grid construction
    int range = sRP[lastLocal] + ((sDG[lastLocal] + 3) & ~3) - rpBeg;
    bool fast = (range <= 2048);
    if (fast) {                            // bulk coalesced NT index stage
        for (int j = t * 4; j < range; j += 1024) {
            int4v v = __builtin_nontemporal_load((const int4v*)(csr4 + rpBeg + j));
            *(int4v*)&sIdx[j] = v;
        }
    }
    __syncthreads();

    int lane = t & 63;
    int wv   = t >> 6;                    // 0..3
    int grp  = lane >> 3;                 // 0..7 (node group within wave)
    int sub  = lane & 7;                  // uint (bf16 pair) within 16-feat chunk
    int li = wv * 8 + grp;                // local node 0..31
    int i = i0 + li;
    bool alive = (i < n);
    const unsigned* hc = h + (size_t)chunk * ((size_t)n * 8);
    float ax = 0.f, ay = 0.f;
    int cnt = 0, off = 0;
    if (alive) {
        cnt = sDG[li];
        off = sRP[li] - rpBeg;
        unsigned u = hc[i * 8 + sub];                             // self (L2 table)
        ax = bflo(u);
        ay = bfhi(u);
    }
    if (fast) {
        int k = 0;
        for (; k + 16 <= cnt; k += 16) {
            unsigned g[16];
            #pragma unroll
            for (int j = 0; j < 16; ++j) {
                int s = sIdx[off + k + j];                        // LDS broadcast
                g[j] = hc[(s << 3) + sub];                        // 32 B granule, L2 hit
            }
            #pragma unroll
            for (int j = 0; j < 16; ++j) {
                ax += bflo(g[j]);
                ay += bfhi(g[j]);
            }
        }
        if (k < cnt) {                    // predicated tail (<=15 edges)
            #pragma unroll
            for (int j = 0; j < 16; ++j) {
                int s = sIdx[off + k + j];                        // in-bounds (IDXCAP slack)
                bool ok = (k + j) < cnt;
                int su = ok ? s : i;                              // clamp to valid row
                unsigned gg = hc[(su << 3) + sub];
                gg = ok ? gg : 0u;
                ax += bflo(gg);
                ay += bfhi(gg);
            }
        }
    } else {                              // fallback: global index path
        int beg = rpBeg + off;
        int k = 0;
        for (; k + 16 <= cnt; k += 16) {
            const int4v* p = (const int4v*)(csr4 + beg + k);
            int4v s0 = __builtin_nontemporal_load(p);
            int4v s1 = __builtin_nontemporal_load(p + 1);
            int4v s2 = __builtin_nontemporal_load(p + 2);
            int4v s3 = __builtin_nontemporal_load(p + 3);
            unsigned g[16];
            #pragma unroll
            for (int j = 0; j < 4; ++j) {
                g[j]      = hc[(s0[j] << 3) + sub];
                g[4 + j]  = hc[(s1[j] << 3) + sub];
                g[8 + j]  = hc[(s2[j] << 3) + sub];
                g[12 + j] = hc[(s3[j] << 3) + sub];
            }
            #pragma unroll
            for (int j = 0; j < 16; ++j) {
                ax += bflo(g[j]);
                ay += bfhi(g[j]);
            }
        }
        if (k < cnt) {
            const int4v* p = (const int4v*)(csr4 + beg + k);
            int4v s0 = __builtin_nontemporal_load(p);
            int4v s1 = __builtin_nontemporal_load(p + 1);
            int4v s2 = __builtin_nontemporal_load(p + 2);
            int4v s3 = __builtin_nontemporal_load(p + 3);
            int sv[16];
            #pragma unroll
            for (int j = 0; j < 4; ++j) {
                sv[j] = s0[j]; sv[4 + j] = s1[j]; sv[8 + j] = s2[j]; sv[12 + j] = s3[j];
            }
            #pragma unroll
            for (int j = 0; j < 16; ++j) {
                bool ok = (k + j) < cnt;
                int su = ok ? sv[j] : i;
                unsigned gg = hc[(su << 3) + sub];
                gg = ok ? gg : 0u;
                ax += bflo(gg);
                ay += bfhi(gg);
            }
        }
    }
    if (alive) {
        float di = rsqrtf((float)(cnt + 1));        // == dinv[i] bit-identically
        unsigned* ab = aggb + (size_t)chunk * ((size_t)n * 8);
        __builtin_nontemporal_store(pack2bf(ax * di, ay * di), &ab[(i << 3) + sub]);
    }
}

// pull 64 feats: out[i] = dinv[i]*(h'[i] + sum h'[s]) + b2. One wave/node.
// dwordx4 index loads (16B-aligned rows) + predicated 8-wide tail.
__global__ __launch_bounds__(256) void k_pull64(const unsigned short* __restrict__ h,
                                                const int* __restrict__ row_ptr,
                                                const int* __restrict__ deg,
                                                const unsigned* __restrict__ csr4,
                                                const float* __restrict__ dinv,
                                                const float* __restrict__ b2,
                                                float* __restrict__ out, int n) {
    int wave = (blockIdx.x * 256 + threadIdx.x) >> 6;
    int lane = threadIdx.x & 63;
    if (wave >= n) return;
    int i = __builtin_amdgcn_readfirstlane(wave);
    float acc = __uint_as_float((unsigned)h[(size_t)i * 64 + lane] << 16);  // self
    int beg = __builtin_nontemporal_load(&row_ptr[i]);
    int cnt = __builtin_nontemporal_load(&deg[i]);
    int k = 0;
    for (; k + 8 <= cnt; k += 8) {
        const int4v* p = (const int4v*)(csr4 + beg + k);
        int4v s0 = __builtin_nontemporal_load(p);
        int4v s1 = __builtin_nontemporal_load(p + 1);
        unsigned short u[8];
        #pragma unroll
        for (int j = 0; j < 4; ++j) {
            u[j]     = h[(size_t)(unsigned)s0[j] * 64 + lane];
            u[4 + j] = h[(size_t)(unsigned)s1[j] * 64 + lane];
        }
        #pragma unroll
        for (int j = 0; j < 8; ++j)
            acc += __uint_as_float((unsigned)u[j] << 16);
    }
    if (k < cnt) {                        // predicated tail (<=7 edges)
        const int4v* p = (const int4v*)(csr4 + beg + k);
        int4v s0 = __builtin_nontemporal_load(p);
        int4v s1 = __builtin_nontemporal_load(p + 1);
        int sv[8];
        #pragma unroll
        for (int j = 0; j < 4; ++j) { sv[j] = s0[j]; sv[4 + j] = s1[j]; }
        #pragma unroll
        for (int j = 0; j < 8; ++j) {
            bool ok = (k + j) < cnt;
            unsigned s = ok ? (unsigned)sv[j] : (unsigned)i;
            unsigned uu = (unsigned)h[(size_t)s * 64 + lane] << 16;
            acc += ok ? __uint_as_float(uu) : 0.f;
        }
    }
    out[(size_t)i * 64 + lane] = acc * dinv[i] + b2[lane];
}

extern "C" void kernel_launch(void* const* d_in, const int* in_sizes, int n_in,
                              void* d_out, int out_size, void* d_ws, size_t ws_size,
                              hipStream_t stream) {
    const float* x  = (const float*)d_in[0];
    const int*   ei = (const int*)d_in[1];
    const float* W1 = (const float*)d_in[2];
    const float* b1 = (const float*)d_in[3];
    const float* W2 = (const float*)d_in[4];
    const float* b2 = (const float*)d_in[5];
    float* out = (float*)d_out;

    const int N = in_sizes[0] / 128;
    const int E = in_sizes[1] / 2;
    const int* src = ei;
    const int* dst = ei + E;
    const int nbuck = (N + BSIZE - 1) >> BSHIFT;        // 196 for N=100000
    const size_t capE = (size_t)nbuck << CAPSH;         // padded edge capacity

    float* dinv     = (float*)d_ws;                     // N
    int*   deg      = (int*)(dinv + N);                 // N
    int*   row_ptr  = deg + N;                          // N
    int*   bcur     = row_ptr + N;                      // 256
    short* w1t      = (short*)(bcur + 256);             // 128*128
    short* w2t      = w1t + 128 * 128;                  // 64*128
    unsigned* csr4  = (unsigned*)(w2t + 64 * 128);      // capE (12.8 MB)
    short* bufH     = (short*)(csr4 + capE);            // N*128 bf16 (h1', chunk-major)
    short* bufH2    = bufH + (size_t)N * 128;           // N*64  bf16 (h2')
    unsigned* aggb  = (unsigned*)(bufH2 + (size_t)N * 64); // N*64 bf16x2 (agg1, chunk-major)
    unsigned* ebuf  = (unsigned*)bufH2;                 // capE uints; aliases
                                                        // bufH2+aggb (ebuf dead
                                                        // before their writes)

    const int ntile = (E + 4095) / 4096;

    // ---- weight prep + bucket cursor init ----
    k_prep<<<97, 256, 0, stream>>>(W1, W2, w1t, w2t, bcur, nbuck);

    // ---- bucketed CSR build (per-node atomics all in LDS) ----
    k_bucket<<<ntile, 256, 0, stream>>>(src, dst, bcur, ebuf, E, nbuck);
    k_bcsr<<<nbuck, BSIZE, 0, stream>>>(ebuf, bcur, deg, row_ptr, dinv, csr4, N);

    // ---- layer 1 ----
    k_gemm1<<<(N + 63) / 64, 256, 0, stream>>>(x, w1t, dinv, bufH, N);
    k_pull128<<<8 * ((N + 31) / 32), 256, 0, stream>>>((const unsigned*)bufH, row_ptr, deg, csr4, aggb, N);

    // ---- layer 2 ----
    k_gemm2<<<(N + 63) / 64, 256, 0, stream>>>(aggb, b1, w2t, dinv, bufH2, N);
    k_pull64<<<(N + 3) / 4, 256, 0, stream>>>((const unsigned short*)bufH2, row_ptr, deg, csr4, dinv, b2, out, N);
}